// Round 1
// baseline (119.033 us; speedup 1.0000x reference)
//
#include <hip/hip_runtime.h>
#include <hip/hip_bf16.h>

typedef unsigned int u32;
typedef unsigned short u16;
typedef __attribute__((ext_vector_type(8))) short short8;   // 8 x bf16 (4 VGPR)
typedef __attribute__((ext_vector_type(4))) float f32x4;
typedef __attribute__((ext_vector_type(2))) u32 u32x2;

#define LOG2E 1.4426950408889634f
#define SCALE 0.17677669529663687f   /* 32^-0.5 */

__device__ __forceinline__ u16 f2bf(float f) {
    u32 u = __builtin_bit_cast(u32, f);
    u += 0x7FFFu + ((u >> 16) & 1u);      // RNE
    return (u16)(u >> 16);
}

// XOR-swizzled element index for [rows][128] / [rows][64] bf16 LDS tiles
__device__ __forceinline__ int sw128(int r, int e) { return r * 128 + (e ^ ((r & 7) << 3)); }
__device__ __forceinline__ int sw64 (int r, int e) { return r * 64  + (e ^ ((r & 7) << 3)); }

__global__ __launch_bounds__(256) void prep_kernel(
    const float* __restrict__ Wq, const float* __restrict__ Wk,
    const float* __restrict__ Wv, const float* __restrict__ Wo,
    const float* __restrict__ bias_table, const int* __restrict__ rel_index,
    u16* __restrict__ wsW, float* __restrict__ wsB)
{
    int idx = blockIdx.x * 256 + threadIdx.x;
    if (idx < 16384) {
        wsW[idx]         = f2bf(Wq[idx] * (SCALE * LOG2E));  // fold scale*log2e into Wq
        wsW[16384 + idx] = f2bf(Wk[idx]);
        wsW[32768 + idx] = f2bf(Wv[idx]);
        wsW[49152 + idx] = f2bf(Wo[idx]);
        int h = idx >> 12, kk = (idx >> 6) & 63, q = idx & 63;
        // biasT[h][kk][q] = bias_table[rel_index[q,kk], h] * log2e
        wsB[idx] = bias_table[rel_index[q * 64 + kk] * 4 + h] * LOG2E;
    }
}

__global__ __launch_bounds__(256, 2) void wattn_kernel(
    const float* __restrict__ x,
    const float* __restrict__ bq, const float* __restrict__ bk,
    const float* __restrict__ bv, const float* __restrict__ bo,
    const u16* __restrict__ Wbf, const float* __restrict__ biasT,
    float* __restrict__ out)
{
    __shared__ u16 x_sm[64 * 128];   // x tile (bf16); later P for waves 0,1
    __shared__ u16 q_sm[64 * 128];   // q' (pre-scaled); later head-concat hc
    __shared__ u16 k_sm[64 * 128];   // k; later P for waves 2,3
    __shared__ u16 vT_sm[128 * 64];  // v transposed: [channel][token]

    const int b    = blockIdx.x;
    const int tid  = threadIdx.x;
    const int wid  = tid >> 6;
    const int lane = tid & 63;
    const int g    = lane >> 4;
    const int c    = lane & 15;

    // ---- stage x -> LDS bf16 (coalesced float4, swizzled store) ----
    {
        const float* xb = x + (size_t)b * 8192;
        #pragma unroll
        for (int it = 0; it < 8; ++it) {
            int idx = it * 1024 + tid * 4;
            float4 v = *(const float4*)(xb + idx);
            int row = idx >> 7, col = idx & 127;
            u32x2 wv;
            wv.x = f2bf(v.x) | ((u32)f2bf(v.y) << 16);
            wv.y = f2bf(v.z) | ((u32)f2bf(v.w) << 16);
            *(u32x2*)&x_sm[sw128(row, col)] = wv;
        }
    }
    __syncthreads();

    // ---- phase A: q/k/v projections. Whole x tile as A-frags in registers ----
    short8 xa[4][4];
    #pragma unroll
    for (int mt = 0; mt < 4; ++mt)
        #pragma unroll
        for (int kt = 0; kt < 4; ++kt)
            xa[mt][kt] = *(const short8*)&x_sm[sw128(16 * mt + c, 32 * kt + 8 * g)];

    #pragma unroll
    for (int jj = 0; jj < 6; ++jj) {
        int job = jj * 4 + wid;          // 24 jobs: (proj p, col-tile nt), weights read once/block
        int p  = job >> 3;
        int nt = job & 7;
        const float* bp = (p == 0) ? bq : (p == 1) ? bk : bv;
        float bcol = bp[16 * nt + c];
        if (p == 0) bcol *= (SCALE * LOG2E);
        f32x4 acc[4];
        #pragma unroll
        for (int mt = 0; mt < 4; ++mt) { f32x4 t = {bcol, bcol, bcol, bcol}; acc[mt] = t; }
        const u16* W = Wbf + p * 16384;
        #pragma unroll
        for (int kt = 0; kt < 4; ++kt) {
            short8 bf = *(const short8*)(W + (16 * nt + c) * 128 + 32 * kt + 8 * g);
            #pragma unroll
            for (int mt = 0; mt < 4; ++mt)
                acc[mt] = __builtin_amdgcn_mfma_f32_16x16x32_bf16(xa[mt][kt], bf, acc[mt], 0, 0, 0);
        }
        if (p < 2) {
            u16* dst = (p == 0) ? q_sm : k_sm;
            #pragma unroll
            for (int mt = 0; mt < 4; ++mt)
                #pragma unroll
                for (int r = 0; r < 4; ++r)
                    dst[sw128(16 * mt + 4 * g + r, 16 * nt + c)] = f2bf(acc[mt][r]);
        } else {  // v: store transposed [channel][token]; C-layout gives 4 consecutive tokens
            #pragma unroll
            for (int mt = 0; mt < 4; ++mt) {
                u32x2 wv;
                wv.x = f2bf(acc[mt][0]) | ((u32)f2bf(acc[mt][1]) << 16);
                wv.y = f2bf(acc[mt][2]) | ((u32)f2bf(acc[mt][3]) << 16);
                *(u32x2*)&vT_sm[sw64(16 * nt + c, 16 * mt + 4 * g)] = wv;
            }
        }
    }
    __syncthreads();

    // ---- phase B: attention, one head per wave. S^T = K·Q^T with bias C-init ----
    const int d0 = 32 * wid;
    short8 ka[4], qb[4];
    #pragma unroll
    for (int t = 0; t < 4; ++t) {
        ka[t] = *(const short8*)&k_sm[sw128(16 * t + c, d0 + 8 * g)];
        qb[t] = *(const short8*)&q_sm[sw128(16 * t + c, d0 + 8 * g)];
    }
    f32x4 accP[4][4];
    const float* bT = biasT + wid * 4096;
    #pragma unroll
    for (int mt = 0; mt < 4; ++mt)
        #pragma unroll
        for (int nt = 0; nt < 4; ++nt) {
            f32x4 ci;
            #pragma unroll
            for (int r = 0; r < 4; ++r)
                ci[r] = bT[(16 * mt + 4 * g + r) * 64 + 16 * nt + c];
            accP[mt][nt] = __builtin_amdgcn_mfma_f32_16x16x32_bf16(ka[mt], qb[nt], ci, 0, 0, 0);
        }
    __syncthreads();   // all x/q/k LDS reads done -> x_sm/k_sm reusable for P, q_sm for hc

    // softmax over kk (rows of S^T): 16 local values per lane + shfl over lane^16, lane^32
    #pragma unroll
    for (int nt = 0; nt < 4; ++nt) {
        float m = accP[0][nt][0];
        #pragma unroll
        for (int mt = 0; mt < 4; ++mt)
            #pragma unroll
            for (int r = 0; r < 4; ++r) m = fmaxf(m, accP[mt][nt][r]);
        m = fmaxf(m, __shfl_xor(m, 16, 64));
        m = fmaxf(m, __shfl_xor(m, 32, 64));
        float s = 0.f;
        #pragma unroll
        for (int mt = 0; mt < 4; ++mt)
            #pragma unroll
            for (int r = 0; r < 4; ++r) {
                float e = exp2f(accP[mt][nt][r] - m);   // scale*log2e folded into Wq, log2e into bias
                accP[mt][nt][r] = e;
                s += e;
            }
        s += __shfl_xor(s, 16, 64);
        s += __shfl_xor(s, 32, 64);
        float rinv = 1.0f / s;
        #pragma unroll
        for (int mt = 0; mt < 4; ++mt)
            #pragma unroll
            for (int r = 0; r < 4; ++r) accP[mt][nt][r] *= rinv;
    }

    // write P[q][kk] bf16 into per-wave region (aliased into dead x_sm/k_sm)
    u16* Pw = ((wid & 2) ? k_sm : x_sm) + (wid & 1) * 4096;
    #pragma unroll
    for (int mt = 0; mt < 4; ++mt)
        #pragma unroll
        for (int nt = 0; nt < 4; ++nt) {
            u32x2 wv;
            wv.x = f2bf(accP[mt][nt][0]) | ((u32)f2bf(accP[mt][nt][1]) << 16);
            wv.y = f2bf(accP[mt][nt][2]) | ((u32)f2bf(accP[mt][nt][3]) << 16);
            *(u32x2*)&Pw[sw64(16 * nt + c, 16 * mt + 4 * g)] = wv;
        }

    // PV: out_h^T = V_h^T · P^T
    f32x4 accO[2][4];
    #pragma unroll
    for (int mD = 0; mD < 2; ++mD)
        #pragma unroll
        for (int nt = 0; nt < 4; ++nt) { f32x4 z = {0.f, 0.f, 0.f, 0.f}; accO[mD][nt] = z; }
    #pragma unroll
    for (int kt = 0; kt < 2; ++kt) {
        short8 va[2];
        #pragma unroll
        for (int mD = 0; mD < 2; ++mD)
            va[mD] = *(const short8*)&vT_sm[sw64(d0 + 16 * mD + c, 32 * kt + 8 * g)];
        #pragma unroll
        for (int nt = 0; nt < 4; ++nt) {
            short8 pb = *(const short8*)&Pw[sw64(16 * nt + c, 32 * kt + 8 * g)];
            #pragma unroll
            for (int mD = 0; mD < 2; ++mD)
                accO[mD][nt] = __builtin_amdgcn_mfma_f32_16x16x32_bf16(va[mD], pb, accO[mD][nt], 0, 0, 0);
        }
    }

    // head output back to [token][channel] in hc (= q_sm); C-rows are 4 consecutive channels
    #pragma unroll
    for (int mD = 0; mD < 2; ++mD)
        #pragma unroll
        for (int nt = 0; nt < 4; ++nt) {
            u32x2 wv;
            wv.x = f2bf(accO[mD][nt][0]) | ((u32)f2bf(accO[mD][nt][1]) << 16);
            wv.y = f2bf(accO[mD][nt][2]) | ((u32)f2bf(accO[mD][nt][3]) << 16);
            *(u32x2*)&q_sm[sw128(16 * nt + c, d0 + 16 * mD + 4 * g)] = wv;
        }
    __syncthreads();

    // ---- phase C: output projection out = hc·Wo^T + bo ----
    short8 ha[4][4];
    #pragma unroll
    for (int mt = 0; mt < 4; ++mt)
        #pragma unroll
        for (int kt = 0; kt < 4; ++kt)
            ha[mt][kt] = *(const short8*)&q_sm[sw128(16 * mt + c, 32 * kt + 8 * g)];
    const u16* Wo_ = Wbf + 3 * 16384;
    #pragma unroll
    for (int j = 0; j < 2; ++j) {
        int nt = wid * 2 + j;
        float bocol = bo[16 * nt + c];
        f32x4 acc[4];
        #pragma unroll
        for (int mt = 0; mt < 4; ++mt) { f32x4 t = {bocol, bocol, bocol, bocol}; acc[mt] = t; }
        #pragma unroll
        for (int kt = 0; kt < 4; ++kt) {
            short8 wf = *(const short8*)(Wo_ + (16 * nt + c) * 128 + 32 * kt + 8 * g);
            #pragma unroll
            for (int mt = 0; mt < 4; ++mt)
                acc[mt] = __builtin_amdgcn_mfma_f32_16x16x32_bf16(ha[mt][kt], wf, acc[mt], 0, 0, 0);
        }
        float* ob = out + (size_t)b * 8192;
        #pragma unroll
        for (int mt = 0; mt < 4; ++mt)
            #pragma unroll
            for (int r = 0; r < 4; ++r)
                ob[(16 * mt + 4 * g + r) * 128 + 16 * nt + c] = acc[mt][r];
    }
}

extern "C" void kernel_launch(void* const* d_in, const int* in_sizes, int n_in,
                              void* d_out, int out_size, void* d_ws, size_t ws_size,
                              hipStream_t stream)
{
    const float* query      = (const float*)d_in[0];
    const float* Wq         = (const float*)d_in[1];
    const float* bq         = (const float*)d_in[2];
    const float* Wk         = (const float*)d_in[3];
    const float* bk         = (const float*)d_in[4];
    const float* Wv         = (const float*)d_in[5];
    const float* bv         = (const float*)d_in[6];
    const float* Wo         = (const float*)d_in[7];
    const float* bo         = (const float*)d_in[8];
    const float* bias_table = (const float*)d_in[9];
    const int*   rel_index  = (const int*)d_in[10];

    u16*   wsW = (u16*)d_ws;                          // 4 x 32 KB bf16 weights
    float* wsB = (float*)((char*)d_ws + 131072);      // biasT [4][64][64] fp32

    prep_kernel<<<dim3(64), dim3(256), 0, stream>>>(Wq, Wk, Wv, Wo, bias_table, rel_index, wsW, wsB);
    wattn_kernel<<<dim3(4096), dim3(256), 0, stream>>>(query, bq, bk, bv, bo, wsW, wsB, (float*)d_out);
}